// Round 3
// baseline (305.499 us; speedup 1.0000x reference)
//
#include <hip/hip_runtime.h>
#include <hip/hip_bf16.h>

#define N_PTS 65536
#define K_CB  8192
#define D_DIM 64
#define CAPS  63   // candidate slots per row; slot 63 holds the count

typedef float f32x4 __attribute__((ext_vector_type(4)));
typedef short s16x8 __attribute__((ext_vector_type(8)));

typedef __attribute__((address_space(1))) const unsigned int gu32;
typedef __attribute__((address_space(3))) unsigned int lu32;

__device__ __forceinline__ unsigned bfpack2(float a, float b) {
    union { __hip_bfloat162 h2; unsigned u; } cv;
    cv.h2 = __float22bfloat162_rn(make_float2(a, b));   // RNE pair cvt (v_cvt_pk_bf16_f32)
    return cv.u;
}

// async global->LDS, 16B/lane; LDS dest = wave-uniform base + laneID*16
__device__ __forceinline__ void gl2lds16(const void* g, void* lds) {
    __builtin_amdgcn_global_load_lds((gu32*)g, (lu32*)lds, 16, 0, 0);
}

// DPP max within 16-lane rows (reduction domain = tx group, DPP-row aligned)
template <int CTRL>
__device__ __forceinline__ float dpp_fmax(float v) {
    int s = __builtin_amdgcn_update_dpp(0, __float_as_int(v), CTRL, 0xf, 0xf, true);
    return fmaxf(v, __int_as_float(s));
}

// ---- node 0: codebook fp32 -> bf16, stored pre-swizzled in LDS-image order ----
// image[k*64 + s*8 + e] = bf16(cb[k][(s ^ (k&7))*8 + e])  -- bit-identical bytes to
// the original in-kernel cbb fill, so coarse scores are unchanged.
__global__ __launch_bounds__(256) void vq_pack(
        const float* __restrict__ cb, unsigned short* __restrict__ cbswz) {
    int g = blockIdx.x * 256 + threadIdx.x;     // one thread per (row, slot-of-8)
    int row = g >> 3, s = g & 7;
    int u = (s ^ (row & 7)) * 8;
    const float4* p = (const float4*)(cb + (size_t)row * D_DIM + u);
    float4 a = p[0], b = p[1];
    uint4 pk;
    pk.x = bfpack2(a.x, a.y); pk.y = bfpack2(a.z, a.w);
    pk.z = bfpack2(b.x, b.y); pk.w = bfpack2(b.z, b.w);
    *(uint4*)(cbswz + (size_t)row * 64 + s * 8) = pk;
}

// ---- node 1: e2[K], x2[N] (numpy-pairwise exact) + per-block e2 maxes ----
__global__ __launch_bounds__(256) void vq_prep(
        const float* __restrict__ z, const float* __restrict__ cb,
        float* __restrict__ e2, float* __restrict__ x2, float* __restrict__ bmax) {
#pragma clang fp contract(off)
    __shared__ float sm[4];
    int b = blockIdx.x;
    int lane = threadIdx.x & 63;
    int wv = threadIdx.x >> 6;
    const float* src; float* dst; int row0;
    if (b < 128) { src = cb; dst = e2; row0 = b * 64 + wv * 16; }
    else         { src = z;  dst = x2; row0 = (b - 128) * 64 + wv * 16; }
    float lmax = 0.f;
    for (int r = 0; r < 16; ++r) {
        int row = row0 + r;
        float v = src[(size_t)row * D_DIM + lane];
        float w = v * v;
        float ra = w;
#pragma unroll
        for (int i = 1; i < 8; ++i) ra = ra + __shfl(w, lane + 8 * i, 64);
        float r0 = __shfl(ra, 0, 64), r1 = __shfl(ra, 1, 64),
              r2 = __shfl(ra, 2, 64), r3 = __shfl(ra, 3, 64),
              r4 = __shfl(ra, 4, 64), r5 = __shfl(ra, 5, 64),
              r6 = __shfl(ra, 6, 64), r7 = __shfl(ra, 7, 64);
        if (lane == 0) {
            float s = ((r0 + r1) + (r2 + r3)) + ((r4 + r5) + (r6 + r7));
            dst[row] = s;
            lmax = fmaxf(lmax, s);
        }
    }
    if (b < 128) {                 // block-uniform branch: syncthreads is safe
        if (lane == 0) sm[wv] = lmax;
        __syncthreads();
        if (threadIdx.x == 0)
            bmax[b] = fmaxf(fmaxf(sm[0], sm[1]), fmaxf(sm[2], sm[3]));
    }
}

// stage one 128-row codebook chunk (16 KB, pre-swizzled) + its e2 slice, async.
// 8 waves x 1 KB per j, 2 j-steps -> 16 KB.
__device__ __forceinline__ void stage_chunk(
        const unsigned short* __restrict__ cbswz, const float* __restrict__ e2,
        unsigned short* bufb, float* e2hb, int kc, int w, int l) {
    const char* gbase = (const char*)(cbswz + (size_t)kc * 128 * 64);
#pragma unroll
    for (int j = 0; j < 2; ++j) {
        int off = j * 8192 + w * 1024;               // wave-uniform LDS base
        gl2lds16(gbase + off + l * 16, (char*)bufb + off);
    }
    if (w == 0 && l < 32)                             // 128 floats, lanes 0..31
        gl2lds16(e2 + (size_t)kc * 128 + l * 4, e2hb);
}

// ---- node 2: single-sweep coarse argmin with online candidate collection ----
// bias -e2/2 in MFMA C-init => t = -2*acc; min-t == max-acc.
// Collect acc >= prefixMax - W/2 (superset guarantee); chunk 0 revisited at end.
// v4: 1024 blocks x 512 threads, 64 z-rows/block. Wave pairs share one 16-row
// group and split the per-chunk ct-range; per-chunk prefix max merged across
// the pair via parity-buffered LDS folded into the chunk barrier. 36 KB LDS
// -> 4 blocks/CU = 32 waves/CU. Candidate-set soundness is prefix-granularity
// invariant (any entry within W/2-delta of the exact min passes EVERY prefix
// threshold), so the rescore argmin -- including exact ties -- is unchanged.
__global__ __launch_bounds__(512, 8) void vq_coarse(
        const float* __restrict__ z, const unsigned short* __restrict__ cbswz,
        const float* __restrict__ e2, const float* __restrict__ x2,
        const float* __restrict__ bmax, int* __restrict__ cand) {
    // pool[0] first 8 KB holds the z tile until A-frags are register-resident,
    // then pool[0]/pool[1] form the 2x16 KB chunk ring.
    __shared__ __align__(16) unsigned short pool[2][128 * 64];   // 32 KB
    __shared__ __align__(16) float e2h[2][128];                  // 1 KB
    __shared__ __align__(16) float mrg[2][2][4][4][4];           // 2 KB [parity][half][rg][q][r]
    __shared__ int cntS[64];
    const int tid = threadIdx.x;
    const int w = tid >> 6, l = tid & 63, tx = l & 15, q = l >> 4;
    const int rg = w >> 1, half = w & 1;   // row-group 0..3, ct-half 0..1
    const int n0 = blockIdx.x * 64;

    if (tid < 64) cntS[tid] = 0;

    // stage z tile fp32->bf16, swizzled (one-time; proven conflict-free layout)
    {
        int row = tid >> 3, u = tid & 7;
        const float4* p = (const float4*)(z + (size_t)(n0 + row) * D_DIM + u * 8);
        float4 a = p[0], b2 = p[1];
        uint4 pk;
        pk.x = bfpack2(a.x, a.y);   pk.y = bfpack2(a.z, a.w);
        pk.z = bfpack2(b2.x, b2.y); pk.w = bfpack2(b2.z, b2.w);
        *(uint4*)&pool[0][row * 64 + ((u ^ (row & 7)) * 8)] = pk;
    }

    float e2m;   // global e2max from prep's per-block maxes
    {
        float v = fmaxf(bmax[l], bmax[l + 64]);
#pragma unroll
        for (int m = 1; m < 64; m <<= 1) v = fmaxf(v, __shfl_xor(v, m, 64));
        e2m = v;
    }

    float halfW[4], A[4], M[4];
#pragma unroll
    for (int i = 0; i < 4; ++i) {
        int row = n0 + rg * 16 + q * 4 + i;
        halfW[i] = 0.0175f * sqrtf(x2[row] * e2m) + 1e-4f;   // W/2, R4-proven constant
        A[i] = 3.0e38f;      // no collection during first chunk
        M[i] = -3.4e38f;
    }
    float Amin = 3.0e38f;

    __syncthreads();                       // z tile visible to all waves
    s16x8 afr[2];                          // A-frags register-resident for whole kernel
#pragma unroll
    for (int ks = 0; ks < 2; ++ks) {
        int row = rg * 16 + tx;            // pair waves duplicate the same frags
        afr[ks] = *(const s16x8*)&pool[0][row * 64 + (((ks * 4 + q) ^ (tx & 7)) * 8)];
    }
    __syncthreads();                       // all waves done with z tile -> pool reusable

    stage_chunk(cbswz, e2, pool[0], e2h[0], 0, w, l);
    __syncthreads();                       // implicit vmcnt(0): chunk 0 resident

    for (int it = 0; it < 65; ++it) {      // 64 chunks + chunk-0 revisit
        const int kc = (it < 64) ? it : 0;
        const int cur = it & 1;
        if (it < 64)                       // issue next-chunk stage BEFORE compute
            stage_chunk(cbswz, e2, pool[cur ^ 1], e2h[cur ^ 1],
                        (it + 1 < 64) ? it + 1 : 0, w, l);

        const unsigned short* cbb = pool[cur];
        const float* e2c = e2h[cur];
#pragma unroll
        for (int c4 = 0; c4 < 4; ++c4) {
            int ct = half * 4 + c4;        // this wave's ct-half of the chunk
            int crow = ct * 16 + tx;
            float bias = -0.5f * e2c[crow];
            s16x8 b0 = *(const s16x8*)&cbb[crow * 64 + ((q ^ (tx & 7)) * 8)];
            s16x8 b1 = *(const s16x8*)&cbb[crow * 64 + (((4 + q) ^ (tx & 7)) * 8)];
            f32x4 acc = {bias, bias, bias, bias};
            acc = __builtin_amdgcn_mfma_f32_16x16x32_bf16(afr[0], b0, acc, 0, 0, 0);
            acc = __builtin_amdgcn_mfma_f32_16x16x32_bf16(afr[1], b1, acc, 0, 0, 0);
            M[0] = fmaxf(M[0], acc[0]);
            M[1] = fmaxf(M[1], acc[1]);
            M[2] = fmaxf(M[2], acc[2]);
            M[3] = fmaxf(M[3], acc[3]);
            // quad-max entry filter: superset of any(acc[r] >= A[r]); exact
            // per-element predicates re-checked inside -> identical candidate set.
            float amax = fmaxf(fmaxf(fmaxf(acc[0], acc[1]), acc[2]), acc[3]);
            if (amax >= Amin) {            // rare; false during it==0 (Amin=3e38)
                int kglob = kc * 128 + crow;
#pragma unroll
                for (int r = 0; r < 4; ++r) {
                    if (acc[r] >= A[r]) {
                        int row = rg * 16 + q * 4 + r;
                        int slot = atomicAdd(&cntS[row], 1);
                        if (slot < CAPS)
                            cand[(size_t)(n0 + row) * 64 + slot] = kglob;
                    }
                }
            }
        }
        if (it < 64) {   // cross-lane (tx) prefix max via DPP, publish for pair wave
#pragma unroll
            for (int i = 0; i < 4; ++i) {
                float v = M[i];
                v = dpp_fmax<0xB1>(v);    // quad_perm [1,0,3,2]  (xor 1)
                v = dpp_fmax<0x4E>(v);    // quad_perm [2,3,0,1]  (xor 2)
                v = dpp_fmax<0x124>(v);   // row_ror:4  (combine quads)
                v = dpp_fmax<0x128>(v);   // row_ror:8  (full 16-lane max)
                M[i] = v;
            }
            if (tx == 0)
                *(float4*)&mrg[it & 1][half][rg][q][0] = make_float4(M[0], M[1], M[2], M[3]);
        }
        __syncthreads();   // buffer handoff + vmcnt drain + mrg visibility
        if (it < 64) {     // merge pair wave's prefix max -> new thresholds
            float4 om = *(const float4*)&mrg[it & 1][half ^ 1][rg][q][0];
            M[0] = fmaxf(M[0], om.x);
            M[1] = fmaxf(M[1], om.y);
            M[2] = fmaxf(M[2], om.z);
            M[3] = fmaxf(M[3], om.w);
#pragma unroll
            for (int i = 0; i < 4; ++i) A[i] = M[i] - halfW[i];
            Amin = fminf(fminf(A[0], A[1]), fminf(A[2], A[3]));
        }
    }
    if (tid < 64) cand[(size_t)(n0 + tid) * 64 + 63] = cntS[tid];
}

// ---- exact fp32 rescore: bit-identical to the round-3/4 passing pipeline ----
__device__ __forceinline__ float exact_score(const float* zr, const float* __restrict__ cb,
                                             const float* __restrict__ e2, float x2v, int k) {
    const float4* c4 = (const float4*)(cb + (size_t)k * D_DIM);
    float g = 0.f;
#pragma unroll
    for (int j = 0; j < 16; ++j) {
        float4 v = c4[j];
        g = fmaf(zr[4 * j + 0], v.x, g);
        g = fmaf(zr[4 * j + 1], v.y, g);
        g = fmaf(zr[4 * j + 2], v.z, g);
        g = fmaf(zr[4 * j + 3], v.w, g);
    }
    return fmaf(-2.f, g, x2v) + e2[k];
}

// ---- node 3: rescore + gather + straight-through write + loss partials ----
// v2: 2 threads per row (512-thread blocks, same 256 rows/block). Candidate
// list split stride-2, merged via shfl_xor(1) under the exact (score, k)
// lexicographic order -> identical argmin. The straight-through write and
// per-row lsum stay sequential in the half==0 thread, and the 256-leaf block
// reduction tree is unchanged -> loss bit-identical.
__global__ __launch_bounds__(512, 2) void vq_rescore(
        const float* __restrict__ z, const float* __restrict__ cb,
        const float* __restrict__ e2, const float* __restrict__ x2,
        int* __restrict__ slots, float* __restrict__ idx_out,
        float* __restrict__ partials) {
    int tid = threadIdx.x;
    int r = tid >> 1, half = tid & 1;
    int n = blockIdx.x * 256 + r;
    float zr[64];
    const float4* z4 = (const float4*)(z + (size_t)n * D_DIM);
#pragma unroll
    for (int i = 0; i < 16; ++i) {
        float4 v = z4[i];
        zr[4 * i] = v.x; zr[4 * i + 1] = v.y; zr[4 * i + 2] = v.z; zr[4 * i + 3] = v.w;
    }
    float x2v = x2[n];
    int cnt = slots[(size_t)n * 64 + 63];
    float bs = 3.4e38f; int bk = 0x7fffffff;
    if (cnt <= CAPS) {
        for (int i = half; i < cnt; i += 2) {
            int k = slots[(size_t)n * 64 + i];
            float s = exact_score(zr, cb, e2, x2v, k);
            if (s < bs || (s == bs && k < bk)) { bs = s; bk = k; }
        }
    }
    // wave-cooperative full scan for overflowed rows (cheap, ~never taken);
    // only the half==0 lane of a pair flags; merge propagates to the partner.
    unsigned long long mask = __ballot(cnt > CAPS && half == 0);
    while (mask) {
        int src = __ffsll((long long)mask) - 1;
        mask &= (mask - 1);
        int rown = __shfl(n, src, 64);
        float x2s = __shfl(x2v, src, 64);
        float zs[64];
        const float4* zz = (const float4*)(z + (size_t)rown * D_DIM);
#pragma unroll
        for (int i = 0; i < 16; ++i) {
            float4 v = zz[i];
            zs[4 * i] = v.x; zs[4 * i + 1] = v.y; zs[4 * i + 2] = v.z; zs[4 * i + 3] = v.w;
        }
        float fb = 3.4e38f; int fk = 0x7fffffff;
        for (int k = (tid & 63); k < K_CB; k += 64) {
            float s = exact_score(zs, cb, e2, x2s, k);
            if (s < fb || (s == fb && k < fk)) { fb = s; fk = k; }
        }
#pragma unroll
        for (int m = 1; m < 64; m <<= 1) {
            float ov = __shfl_xor(fb, m, 64);
            int   ok = __shfl_xor(fk, m, 64);
            if (ov < fb || (ov == fb && ok < fk)) { fb = ov; fk = ok; }
        }
        if ((tid & 63) == src) { bs = fb; bk = fk; }
    }
    // pair merge: exact lexicographic (score, k) min over both halves
    {
        float ov = __shfl_xor(bs, 1, 64);
        int   ok = __shfl_xor(bk, 1, 64);
        if (ov < bs || (ov == bs && ok < bk)) { bs = ov; bk = ok; }
    }
    __threadfence_block();   // all slot reads drained before aliased zq writes

    __shared__ float red[256];
    if (half == 0) {
        idx_out[n] = (float)bk;
        float lsum = 0.f;
        const float4* c4 = (const float4*)(cb + (size_t)bk * D_DIM);
        float4* o4 = (float4*)((float*)slots + (size_t)n * 64);   // own slot, float view
#pragma unroll
        for (int j = 0; j < 16; ++j) {
            float4 c = c4[j];
            float4 o;
            float d0 = c.x - zr[4 * j];     o.x = zr[4 * j]     + d0;
            float d1 = c.y - zr[4 * j + 1]; o.y = zr[4 * j + 1] + d1;
            float d2 = c.z - zr[4 * j + 2]; o.z = zr[4 * j + 2] + d2;
            float d3 = c.w - zr[4 * j + 3]; o.w = zr[4 * j + 3] + d3;
            lsum += d0 * d0 + d1 * d1 + d2 * d2 + d3 * d3;
            o4[j] = o;
        }
        red[r] = lsum;
    }
    __syncthreads();
    for (int s = 128; s > 0; s >>= 1) {
        if (tid < s) red[tid] += red[tid + s];
        __syncthreads();
    }
    if (tid == 0) partials[blockIdx.x] = red[0];
}

// ---- node 4: final loss ----
__global__ void vq_final(const float* __restrict__ partials, float* __restrict__ loss_out) {
    __shared__ float red[256];
    int tid = threadIdx.x;
    red[tid] = partials[tid];
    __syncthreads();
    for (int s = 128; s > 0; s >>= 1) {
        if (tid < s) red[tid] += red[tid + s];
        __syncthreads();
    }
    if (tid == 0) *loss_out = 1.25f * red[0] / (float)(N_PTS * D_DIM);
}

extern "C" void kernel_launch(void* const* d_in, const int* in_sizes, int n_in,
                              void* d_out, int out_size, void* d_ws, size_t ws_size,
                              hipStream_t stream) {
    const float* z  = (const float*)d_in[0];
    const float* cb = (const float*)d_in[1];
    float* out      = (float*)d_out;
    float* zq_out   = out;                          // [N*64]; doubles as cand slots
    float* loss_out = out + (size_t)N_PTS * D_DIM;  // [1]
    float* idx_out  = loss_out + 1;                 // [N]; [0..127] doubles as bmax scratch

    // workspace: partials(256f) | e2(K f) | x2(N f) | cbswz(K*64 bf16, 1 MB)
    float* wsf = (float*)d_ws;
    float* partials = wsf;
    float* e2 = wsf + 256;
    float* x2 = wsf + 256 + K_CB;
    unsigned short* cbswz = (unsigned short*)(wsf + 256 + K_CB + N_PTS);  // 16B-aligned

    int* cand = (int*)zq_out;
    float* bmax = idx_out;                          // overwritten by rescore afterwards

    vq_pack   <<<K_CB * 8 / 256, 256, 0, stream>>>(cb, cbswz);
    vq_prep   <<<128 + N_PTS / 64, 256, 0, stream>>>(z, cb, e2, x2, bmax);
    vq_coarse <<<N_PTS / 64, 512, 0, stream>>>(z, cbswz, e2, x2, bmax, cand);
    vq_rescore<<<N_PTS / 256, 512, 0, stream>>>(z, cb, e2, x2, cand, idx_out, partials);
    vq_final  <<<1, 256, 0, stream>>>(partials, loss_out);
}